// Round 3
// baseline (216.667 us; speedup 1.0000x reference)
//
#include <hip/hip_runtime.h>

#define RREG 36
#define TTOK 64
#define DDIM 1024

typedef __attribute__((ext_vector_type(4))) float f32x4;
typedef __attribute__((ext_vector_type(8))) short bf16x8;

__device__ __forceinline__ unsigned short f2bf(float x) {
  unsigned int u = __float_as_uint(x);
  u += 0x7fffu + ((u >> 16) & 1u);   // round-to-nearest-even
  return (unsigned short)(u >> 16);
}

__device__ __forceinline__ bf16x8 cvt8(float4 a, float4 b) {
  bf16x8 r;
  r[0] = (short)f2bf(a.x); r[1] = (short)f2bf(a.y);
  r[2] = (short)f2bf(a.z); r[3] = (short)f2bf(a.w);
  r[4] = (short)f2bf(b.x); r[5] = (short)f2bf(b.y);
  r[6] = (short)f2bf(b.z); r[7] = (short)f2bf(b.w);
  return r;
}

// Barrier-free fused SCAN kernel. One block per batch (256 blocks x 1024 thr).
// Phase A: each of 12 waves loads its own MFMA fragments straight from global
//   (img rows + cap rows, fp32), converts to bf16 in registers, accumulates
//   dots. Redundant reads across waves (img x4, cap x3) dedup in L1/L2.
//   No LDS staging, no barriers -> 16 independent dwordx4 loads in flight per
//   lane per chunk; waves overlap each other's latency freely.
// Phase B: img is L2/L3-resident; waves load B-fragment columns directly from
//   global (b32, 64B segments), attn fragment from LDS once. No barriers.
// Only 2 __syncthreads() in the kernel (around the softmax).
__global__ __launch_bounds__(1024, 4) void scan_fused(
    const float* __restrict__ img, const float* __restrict__ cap,
    float* __restrict__ out) {
  __shared__ __align__(16) float ssc[48 * 66];            // raw dots [r][t]
  __shared__ __align__(16) unsigned short satt[64 * 48];  // attn^T, cols>=36 zero
  __shared__ float sni[48];                               // img norms
  __shared__ float snc[TTOK];                             // cap norms

  const int tid  = threadIdx.x;
  const int lane = tid & 63;
  const int wave = tid >> 6;        // 0..15
  const int fm   = lane & 15;
  const int kq   = lane >> 4;
  const int b    = blockIdx.x;

  const float* imgb = img + (size_t)b * RREG * DDIM;
  const float* capb = cap + (size_t)b * TTOK * DDIM;
  float*       outb = out + (size_t)b * TTOK * DDIM;

  // ---------------- Phase A: dots = img(36x1024) . cap^T(1024x64) ----------------
  if (wave < 12) {
    const int mt = wave >> 2;       // img row tile 0..2
    const int nt = wave & 3;        // cap row tile 0..3
    const int ar = mt * 16 + fm;    // img row 0..47 (>=36 -> zero frag)
    const int br = nt * 16 + fm;    // cap row 0..63
    const bool avld = (ar < RREG);
    const float* ap = imgb + (size_t)ar * DDIM + kq * 8;
    const float* bp = capb + (size_t)br * DDIM + kq * 8;

    f32x4 acc = {0.f, 0.f, 0.f, 0.f};
    float nI = 0.f, nC = 0.f;
    const float4 z4 = make_float4(0.f, 0.f, 0.f, 0.f);

    for (int c = 0; c < 8; ++c) {
      float4 A0[4], A1[4], B0[4], B1[4];
#pragma unroll
      for (int ks = 0; ks < 4; ++ks) {   // 16 independent dwordx4: batched issue
        const float* a = ap + c * 128 + ks * 32;
        const float* q = bp + c * 128 + ks * 32;
        A0[ks] = avld ? *(const float4*)(a)     : z4;
        A1[ks] = avld ? *(const float4*)(a + 4) : z4;
        B0[ks] = *(const float4*)(q);
        B1[ks] = *(const float4*)(q + 4);
      }
#pragma unroll
      for (int ks = 0; ks < 4; ++ks) {
        nI += A0[ks].x * A0[ks].x + A0[ks].y * A0[ks].y +
              A0[ks].z * A0[ks].z + A0[ks].w * A0[ks].w +
              A1[ks].x * A1[ks].x + A1[ks].y * A1[ks].y +
              A1[ks].z * A1[ks].z + A1[ks].w * A1[ks].w;
        nC += B0[ks].x * B0[ks].x + B0[ks].y * B0[ks].y +
              B0[ks].z * B0[ks].z + B0[ks].w * B0[ks].w +
              B1[ks].x * B1[ks].x + B1[ks].y * B1[ks].y +
              B1[ks].z * B1[ks].z + B1[ks].w * B1[ks].w;
        acc = __builtin_amdgcn_mfma_f32_16x16x32_bf16(
            cvt8(A0[ks], A1[ks]), cvt8(B0[ks], B1[ks]), acc, 0, 0, 0);
      }
    }
    // dump raw dots: D row=(kq*4+i)=r-sub, col=fm=t-sub
#pragma unroll
    for (int i = 0; i < 4; ++i)
      ssc[(mt * 16 + kq * 4 + i) * 66 + nt * 16 + fm] = acc[i];
    // norms: reduce the kq-slices (lanes 16 apart hold disjoint d-slices)
    nI += __shfl_xor(nI, 16); nI += __shfl_xor(nI, 32);
    nC += __shfl_xor(nC, 16); nC += __shfl_xor(nC, 32);
    if (nt == 0 && kq == 0 && avld) sni[ar] = sqrtf(nI);
    if (mt == 0 && kq == 0)         snc[br] = sqrtf(nC);
  }
  __syncthreads();

  // ---------------- softmax over r, per t (wave 0; lane = t) ----------------
  if (wave == 0) {
    float cn = snc[lane];
    float s[RREG];
    float mx = -1e30f;
#pragma unroll
    for (int r = 0; r < RREG; ++r) {
      float denom = fmaxf(sni[r] * cn, 1e-8f);
      float v = ssc[r * 66 + lane] / denom;
      s[r] = v;
      mx = fmaxf(mx, v);
    }
    float sum = 0.f;
#pragma unroll
    for (int r = 0; r < RREG; ++r) { float e = __expf(s[r] - mx); s[r] = e; sum += e; }
    float rinv = 1.f / sum;
    unsigned short* ap2 = satt + lane * 48;
#pragma unroll
    for (int r = 0; r < RREG; ++r) ap2[r] = f2bf(s[r] * rinv);
#pragma unroll
    for (int r = RREG; r < 48; ++r) ap2[r] = 0;
  }
  __syncthreads();

  // ---------------- Phase B: out = attn^T(64x36) . img(36x1024) ----------------
  const int mtB = wave >> 2;   // t-tile 0..3
  const unsigned short* arowB = satt + (mtB * 16 + fm) * 48;
  bf16x8 a1 = *(const bf16x8*)(arowB + kq * 8);            // k = 0..31
  bf16x8 a2 = {0, 0, 0, 0, 0, 0, 0, 0};                    // k = 32..47 (zeros >=36)
  if (kq < 2) a2 = *(const bf16x8*)(arowB + 32 + kq * 8);

  for (int cb = 0; cb < 8; ++cb) {
#pragma unroll
    for (int j = 0; j < 2; ++j) {
      const int d = cb * 128 + ((wave & 3) * 2 + j) * 16 + fm;
      const float* cp = imgb + d;       // column d of img, rows via stride DDIM
      float bvx[8];
#pragma unroll
      for (int r = 0; r < 8; ++r)       // 8 independent b32 column loads (L2-hot)
        bvx[r] = cp[(size_t)(kq * 8 + r) * DDIM];
      bf16x8 b1;
#pragma unroll
      for (int r = 0; r < 8; ++r) b1[r] = (short)f2bf(bvx[r]);
      bf16x8 b2 = {0, 0, 0, 0, 0, 0, 0, 0};
      if (kq == 0) {                    // rows 32..35 real; 36..47 stay zero
#pragma unroll
        for (int r = 0; r < 4; ++r) b2[r] = (short)f2bf(cp[(size_t)(32 + r) * DDIM]);
      }
      f32x4 o = {0.f, 0.f, 0.f, 0.f};
      o = __builtin_amdgcn_mfma_f32_16x16x32_bf16(a1, b1, o, 0, 0, 0);
      o = __builtin_amdgcn_mfma_f32_16x16x32_bf16(a2, b2, o, 0, 0, 0);
#pragma unroll
      for (int i = 0; i < 4; ++i)
        outb[(size_t)(mtB * 16 + kq * 4 + i) * DDIM + d] = o[i];
    }
  }
}

extern "C" void kernel_launch(void* const* d_in, const int* in_sizes, int n_in,
                              void* d_out, int out_size, void* d_ws, size_t ws_size,
                              hipStream_t stream) {
  const float* img = (const float*)d_in[0];   // (256, 36, 1024) fp32
  const float* cap = (const float*)d_in[1];   // (256, 64, 1024) fp32
  // d_in[2] = cap_mask, unused by reference forward
  float* out = (float*)d_out;                 // (256, 64, 1024) fp32
  scan_fused<<<dim3(256), dim3(1024), 0, stream>>>(img, cap, out);
}

// Round 4
// 178.899 us; speedup vs baseline: 1.2111x; 1.2111x over previous
//
#include <hip/hip_runtime.h>

#define RREG 36
#define TTOK 64
#define DDIM 1024

#define BUFSZ  28672    // one half-chunk buffer: cap 64*256 + img 48*256 bytes
#define IMGOFF 16384    // img region offset inside a buffer
#define SMEMSZ 86016    // 3 buffers

typedef __attribute__((ext_vector_type(4))) float f32x4;
typedef __attribute__((ext_vector_type(8))) short bf16x8;

__device__ __forceinline__ unsigned short f2bf(float x) {
  unsigned int u = __float_as_uint(x);
  u += 0x7fffu + ((u >> 16) & 1u);   // round-to-nearest-even
  return (unsigned short)(u >> 16);
}

__device__ __forceinline__ bf16x8 cvt8(float4 a, float4 b) {
  bf16x8 r;
  r[0] = (short)f2bf(a.x); r[1] = (short)f2bf(a.y);
  r[2] = (short)f2bf(a.z); r[3] = (short)f2bf(a.w);
  r[4] = (short)f2bf(b.x); r[5] = (short)f2bf(b.y);
  r[6] = (short)f2bf(b.z); r[7] = (short)f2bf(b.w);
  return r;
}

__device__ __forceinline__ float sq8(float4 a, float4 b) {
  return a.x*a.x + a.y*a.y + a.z*a.z + a.w*a.w +
         b.x*b.x + b.y*b.y + b.z*b.z + b.w*b.w;
}

// async 16B global->LDS DMA (vmcnt-tracked; compiler cannot sink/drain it)
__device__ __forceinline__ void async16(void* lds, const void* g) {
  __builtin_amdgcn_global_load_lds(
      (const __attribute__((address_space(1))) unsigned int*)g,
      (__attribute__((address_space(3))) unsigned int*)lds, 16, 0, 0);
}

// Staging for half-chunk hc (64 floats = 256B per row).
// LDS is linear (gload_lds requirement); the bank-deconflict swizzle
// off ^= (row&7)<<4 is applied to the per-lane GLOBAL source address, and the
// same XOR on the read side (involution => correct data under swizzled reads).
__device__ __forceinline__ void issue_hc(
    unsigned char* smem, int hc, int wave, int lane,
    const unsigned char* capb8, const unsigned char* imgb8,
    int srow, int ssw, int irc) {
  unsigned char* buf = smem + (hc % 3) * BUFSZ;
  // cap rows 0..63: wave w stages rows 4w..4w+3 (lane>>4 selects row, 16 lanes/row)
  async16(buf + (wave << 10) + (lane << 4),
          capb8 + ((size_t)srow << 12) + ((size_t)hc << 8) + ssw);
  // img rows 0..47 (rows>=36 clamped to a valid row; garbage rows never read)
  if (wave < 12)
    async16(buf + IMGOFF + (wave << 10) + (lane << 4),
            imgb8 + ((size_t)irc << 12) + ((size_t)hc << 8) + ssw);
}

__global__ __launch_bounds__(1024, 4) void scan_fused(
    const float* __restrict__ img, const float* __restrict__ cap,
    float* __restrict__ out) {
  __shared__ __align__(16) unsigned char smem[SMEMSZ];

  // epilogue aliases (all inside buffer 0, dead after the K-loop):
  float* ssc  = (float*)(smem);            // [48][66] raw dots
  float* satt = (float*)(smem + 13056);    // [64][40] attn fp32, t-major
  float* sni  = (float*)(smem + 23296);    // [48] img norms
  float* snc  = (float*)(smem + 23488);    // [64] cap norms

  const int tid  = threadIdx.x;
  const int lane = tid & 63;
  const int wave = tid >> 6;        // 0..15
  const int fm   = lane & 15;
  const int kq   = lane >> 4;
  const int b    = blockIdx.x;

  const float* imgb = img + (size_t)b * RREG * DDIM;
  const float* capb = cap + (size_t)b * TTOK * DDIM;
  float*       outb = out + (size_t)b * TTOK * DDIM;
  const unsigned char* capb8 = (const unsigned char*)capb;
  const unsigned char* imgb8 = (const unsigned char*)imgb;

  // staging constants
  const int srow = (wave << 2) + (lane >> 4);         // row this lane stages
  const int soff = (lane & 15) << 4;                  // byte within 256B row
  const int ssw  = soff ^ ((srow & 7) << 4);          // swizzled source byte
  const int irc  = srow < RREG ? srow : srow - RREG;  // img row clamp (stays in-bounds)

  const int mt = wave >> 2;   // MFMA tile coords (waves 0..11)
  const int nt = wave & 3;

  f32x4 acc = {0.f, 0.f, 0.f, 0.f};
  float nI = 0.f, nC = 0.f;

  // ---------------- Phase A: dots = img(36x1024) . cap^T(1024x64) ----------------
  // 16 half-chunks of K=64; triple-buffered async DMA, depth-2 prefetch,
  // ONE barrier per step, counted vmcnt (never 0 inside the loop).
  issue_hc(smem, 0, wave, lane, capb8, imgb8, srow, ssw, irc);
  issue_hc(smem, 1, wave, lane, capb8, imgb8, srow, ssw, irc);

#pragma unroll
  for (int c = 0; c < 16; ++c) {
    if (c < 15) {  // own outstanding: hc c (2 or 1) + hc c+1 (2 or 1); keep c+1 in flight
      if (wave < 12) asm volatile("s_waitcnt vmcnt(2)" ::: "memory");
      else           asm volatile("s_waitcnt vmcnt(1)" ::: "memory");
    } else {
      asm volatile("s_waitcnt vmcnt(0)" ::: "memory");
    }
    __builtin_amdgcn_s_barrier();
    asm volatile("" ::: "memory");
    if (c < 14)
      issue_hc(smem, c + 2, wave, lane, capb8, imgb8, srow, ssw, irc);
    if (wave < 12) {
      const unsigned char* buf = smem + (c % 3) * BUFSZ;
      const int arow = mt * 16 + fm;
      const int brow = nt * 16 + fm;
      const unsigned char* ap = buf + IMGOFF + (arow << 8);
      const unsigned char* bp = buf + (brow << 8);
      const int sA = (arow & 7) << 4;
      const int sB = (brow & 7) << 4;
#pragma unroll
      for (int ks = 0; ks < 2; ++ks) {
        const int cb = (kq << 5) + (ks << 7);
        float4 a0 = *(const float4*)(ap + ((cb     ) ^ sA));
        float4 a1 = *(const float4*)(ap + ((cb + 16) ^ sA));
        float4 b0 = *(const float4*)(bp + ((cb     ) ^ sB));
        float4 b1 = *(const float4*)(bp + ((cb + 16) ^ sB));
        if (nt == 0) nI += sq8(a0, a1);   // exact fp32 norms from staged data
        if (mt == 0) nC += sq8(b0, b1);
        acc = __builtin_amdgcn_mfma_f32_16x16x32_bf16(
            cvt8(a0, a1), cvt8(b0, b1), acc, 0, 0, 0);
      }
    }
  }

  // K-loop done; buffer 0 is dead -> becomes ssc/satt/norms region
  __builtin_amdgcn_s_barrier();
  asm volatile("" ::: "memory");

  if (wave < 12) {
#pragma unroll
    for (int i = 0; i < 4; ++i)
      ssc[(mt * 16 + kq * 4 + i) * 66 + nt * 16 + fm] = acc[i];
    nI += __shfl_xor(nI, 16); nI += __shfl_xor(nI, 32);
    nC += __shfl_xor(nC, 16); nC += __shfl_xor(nC, 32);
    const int ar = mt * 16 + fm, br = nt * 16 + fm;
    if (nt == 0 && kq == 0 && ar < RREG) sni[ar] = sqrtf(nI);
    if (mt == 0 && kq == 0)              snc[br] = sqrtf(nC);
  }

  // phase-B img column prefetch: coalesced 256B row segments; issued here so
  // the load latency hides under the softmax (vmcnt, not drained by barriers)
  float ic[RREG];
#pragma unroll
  for (int r = 0; r < RREG; ++r) ic[r] = imgb[r * DDIM + tid];

  asm volatile("s_waitcnt lgkmcnt(0)" ::: "memory");
  __builtin_amdgcn_s_barrier();
  asm volatile("" ::: "memory");

  // ---------------- softmax over r, per t (all 16 waves; 16 lanes per token) ----
  {
    const int tok = (wave << 2) | (lane >> 4);
    const int rr  = lane & 15;
    const float cnv = snc[tok];
    const float s0v = ssc[rr * 66 + tok]        / fmaxf(sni[rr] * cnv, 1e-8f);
    const float s1v = ssc[(rr + 16) * 66 + tok] / fmaxf(sni[rr + 16] * cnv, 1e-8f);
    float s2v = -1e30f;
    if (rr < 4) s2v = ssc[(rr + 32) * 66 + tok] / fmaxf(sni[rr + 32] * cnv, 1e-8f);
    float mx = fmaxf(fmaxf(s0v, s1v), s2v);
#pragma unroll
    for (int o = 8; o > 0; o >>= 1) mx = fmaxf(mx, __shfl_xor(mx, o));
    const float e0 = __expf(s0v - mx);
    const float e1 = __expf(s1v - mx);
    const float e2 = (rr < 4) ? __expf(s2v - mx) : 0.f;
    float sm = e0 + e1 + e2;
#pragma unroll
    for (int o = 8; o > 0; o >>= 1) sm += __shfl_xor(sm, o);
    const float rinv = 1.f / sm;
    satt[tok * 40 + rr]      = e0 * rinv;
    satt[tok * 40 + rr + 16] = e1 * rinv;
    if (rr < 4) satt[tok * 40 + rr + 32] = e2 * rinv;
  }

  asm volatile("s_waitcnt lgkmcnt(0)" ::: "memory");
  __builtin_amdgcn_s_barrier();
  asm volatile("" ::: "memory");

  // ---------------- Phase B: out[t][d] = sum_r attn[r][t] * img[r][d] ----------
  // Pure fp32 VALU streaming: thread owns column d=tid (img col in registers),
  // attn via broadcast float4 LDS reads, coalesced 256B stores. No barriers.
#pragma unroll 2
  for (int t = 0; t < TTOK; ++t) {
    const float4* ap4 = (const float4*)(satt + t * 40);
    float p0 = 0.f, p1 = 0.f, p2 = 0.f, p3 = 0.f;
#pragma unroll
    for (int r4 = 0; r4 < 9; ++r4) {
      float4 a4 = ap4[r4];
      p0 += a4.x * ic[r4 * 4 + 0];
      p1 += a4.y * ic[r4 * 4 + 1];
      p2 += a4.z * ic[r4 * 4 + 2];
      p3 += a4.w * ic[r4 * 4 + 3];
    }
    outb[(size_t)t * DDIM + tid] = (p0 + p1) + (p2 + p3);
  }
}

extern "C" void kernel_launch(void* const* d_in, const int* in_sizes, int n_in,
                              void* d_out, int out_size, void* d_ws, size_t ws_size,
                              hipStream_t stream) {
  const float* img = (const float*)d_in[0];   // (256, 36, 1024) fp32
  const float* cap = (const float*)d_in[1];   // (256, 64, 1024) fp32
  // d_in[2] = cap_mask, unused by reference forward
  float* out = (float*)d_out;                 // (256, 64, 1024) fp32
  scan_fused<<<dim3(256), dim3(1024), 0, stream>>>(img, cap, out);
}

// Round 5
// 173.638 us; speedup vs baseline: 1.2478x; 1.0303x over previous
//
#include <hip/hip_runtime.h>

#define RREG 36
#define TTOK 64
#define DDIM 1024

// LDS geometry (bytes)
#define IMG_STRIDE 1032                         // img row stride, elements (8 pad: 2-way banks)
#define CAP_STRIDE 264                          // cap row stride, elements (8 pad: 2-way banks)
#define IMG_BYTES    (RREG * IMG_STRIDE * 2)    // 74304  persistent bf16 img [36][1032]
#define CAPBUF_BYTES (TTOK * CAP_STRIDE * 2)    // 33792  one K=256 cap panel [64][264]
#define OFF_CAP0  IMG_BYTES                     // 74304
#define OFF_CAP1  (OFF_CAP0 + CAPBUF_BYTES)     // 108096
#define OFF_SSC   (OFF_CAP1 + CAPBUF_BYTES)     // 141888  [48][66] f32 raw dots
#define OFF_SNI   (OFF_SSC + 48 * 66 * 4)       // 154560  [48] f32 img norms
#define OFF_SNC   (OFF_SNI + 192)               // 154752  [64] f32 cap norms
#define SMEMSZ    (OFF_SNC + 256)               // 155008
#define OFF_SATT  OFF_CAP0                      // attn fp32 [64][40], aliases cap buf0 (dead)

typedef __attribute__((ext_vector_type(4))) float f32x4;
typedef __attribute__((ext_vector_type(8))) short bf16x8;

__device__ __forceinline__ unsigned short f2bf(float x) {
  unsigned int u = __float_as_uint(x);
  u += 0x7fffu + ((u >> 16) & 1u);   // round-to-nearest-even
  return (unsigned short)(u >> 16);
}

__device__ __forceinline__ bf16x8 cvt8(float4 a, float4 b) {
  bf16x8 r;
  r[0] = (short)f2bf(a.x); r[1] = (short)f2bf(a.y);
  r[2] = (short)f2bf(a.z); r[3] = (short)f2bf(a.w);
  r[4] = (short)f2bf(b.x); r[5] = (short)f2bf(b.y);
  r[6] = (short)f2bf(b.z); r[7] = (short)f2bf(b.w);
  return r;
}

__device__ __forceinline__ float sq4(float4 a) {
  return a.x*a.x + a.y*a.y + a.z*a.z + a.w*a.w;
}

// lgkm-only barrier: LDS ops drained, prefetched global loads stay in flight
__device__ __forceinline__ void lds_barrier() {
  asm volatile("s_waitcnt lgkmcnt(0)" ::: "memory");
  __builtin_amdgcn_s_barrier();
}

// Coarse-panel fused SCAN: 4 panels of K=256, ONE barrier per panel.
// img staged once (bf16, persistent); phase B is barrier-free VALU from LDS.
__global__ __launch_bounds__(1024, 4) void scan_fused(
    const float* __restrict__ img, const float* __restrict__ cap,
    float* __restrict__ out) {
  __shared__ __align__(16) unsigned char smem[SMEMSZ];

  unsigned short* simg = (unsigned short*)smem;       // [36][1032] bf16 persistent
  float* ssc  = (float*)(smem + OFF_SSC);
  float* sni  = (float*)(smem + OFF_SNI);
  float* snc  = (float*)(smem + OFF_SNC);
  float* satt = (float*)(smem + OFF_SATT);

  const int tid  = threadIdx.x;
  const int lane = tid & 63;
  const int wave = tid >> 6;        // 0..15
  const int fm   = lane & 15;
  const int kq   = lane >> 4;
  const int b    = blockIdx.x;

  const float* imgb = img + (size_t)b * RREG * DDIM;
  const float* capb = cap + (size_t)b * TTOK * DDIM;
  float*       outb = out + (size_t)b * TTOK * DDIM;

  // staging map: 16 threads per row, each owns 16 consecutive floats
  const int ctr = tid >> 4;             // cap row 0..63
  const int cc  = (tid & 15) << 4;      // float col base within panel (0..240)
  const bool hasI = (tid < 16 * RREG);  // threads 0..575 also stage img row ctr (0..35)

  // MFMA tiling (waves 0..11): A-rows mt*16+fm (>=36 -> zero frag), B-rows nt*16+fm
  const int mt = wave >> 2;
  const int nt = wave & 3;
  const int arow = mt * 16 + fm;
  const int brow = nt * 16 + fm;
  const bool avld = (arow < RREG);

  f32x4 acc = {0.f, 0.f, 0.f, 0.f};
  float nC = 0.f, nI = 0.f;
  const bf16x8 zb = {0, 0, 0, 0, 0, 0, 0, 0};

  // ---------------- Phase A: 4 panels of K=256 ----------------
#pragma unroll
  for (int p = 0; p < 4; ++p) {
    // ---- stage panel p: 4-8 independent float4 loads per thread (one batch) ----
    {
      const float* cp = capb + (size_t)ctr * DDIM + p * 256 + cc;
      float4 c0 = *(const float4*)(cp + 0);
      float4 c1 = *(const float4*)(cp + 4);
      float4 c2 = *(const float4*)(cp + 8);
      float4 c3 = *(const float4*)(cp + 12);
      float4 i0, i1, i2, i3;
      if (hasI) {
        const float* ip = imgb + (size_t)ctr * DDIM + p * 256 + cc;
        i0 = *(const float4*)(ip + 0);
        i1 = *(const float4*)(ip + 4);
        i2 = *(const float4*)(ip + 8);
        i3 = *(const float4*)(ip + 12);
      }
      nC += sq4(c0) + sq4(c1) + sq4(c2) + sq4(c3);
      unsigned short* cw = (unsigned short*)(smem + OFF_CAP0 + (p & 1) * CAPBUF_BYTES)
                           + ctr * CAP_STRIDE + cc;
      *(bf16x8*)(cw + 0) = cvt8(c0, c1);
      *(bf16x8*)(cw + 8) = cvt8(c2, c3);
      if (hasI) {
        nI += sq4(i0) + sq4(i1) + sq4(i2) + sq4(i3);
        unsigned short* iw = simg + ctr * IMG_STRIDE + p * 256 + cc;
        *(bf16x8*)(iw + 0) = cvt8(i0, i1);
        *(bf16x8*)(iw + 8) = cvt8(i2, i3);
      }
    }
    lds_barrier();
    // ---- MFMA panel p: 8 k-steps, no further sync (next stage hits other buffer) ----
    if (wave < 12) {
      const unsigned short* ab = simg + arow * IMG_STRIDE + p * 256 + kq * 8;
      const unsigned short* bb = (const unsigned short*)(smem + OFF_CAP0 + (p & 1) * CAPBUF_BYTES)
                                 + brow * CAP_STRIDE + kq * 8;
#pragma unroll
      for (int ks = 0; ks < 8; ++ks) {
        bf16x8 av = avld ? *(const bf16x8*)(ab + ks * 32) : zb;
        bf16x8 bv = *(const bf16x8*)(bb + ks * 32);
        acc = __builtin_amdgcn_mfma_f32_16x16x32_bf16(av, bv, acc, 0, 0, 0);
      }
    }
  }

  // ---------------- epilogue of phase A: dots + norms ----------------
  if (wave < 12) {
#pragma unroll
    for (int i = 0; i < 4; ++i)
      ssc[(mt * 16 + kq * 4 + i) * 66 + nt * 16 + fm] = acc[i];
  }
  // norm reduction within each 16-thread row group
#pragma unroll
  for (int off = 8; off > 0; off >>= 1) {
    nC += __shfl_down(nC, off, 16);
    nI += __shfl_down(nI, off, 16);
  }
  if ((tid & 15) == 0) {
    snc[ctr] = sqrtf(nC);
    if (hasI) sni[ctr] = sqrtf(nI);
  }
  lds_barrier();

  // ---------------- softmax over r, per t (all 16 waves; 16 lanes/token) ----------
  {
    const int tok = (wave << 2) | (lane >> 4);
    const int rr  = lane & 15;
    const float cnv = snc[tok];
    const float s0v = ssc[rr * 66 + tok]        / fmaxf(sni[rr] * cnv, 1e-8f);
    const float s1v = ssc[(rr + 16) * 66 + tok] / fmaxf(sni[rr + 16] * cnv, 1e-8f);
    float s2v = -1e30f;
    if (rr < 4) s2v = ssc[(rr + 32) * 66 + tok] / fmaxf(sni[rr + 32] * cnv, 1e-8f);
    float mx = fmaxf(fmaxf(s0v, s1v), s2v);
#pragma unroll
    for (int o = 8; o > 0; o >>= 1) mx = fmaxf(mx, __shfl_xor(mx, o));
    const float e0 = __expf(s0v - mx);
    const float e1 = __expf(s1v - mx);
    const float e2 = (rr < 4) ? __expf(s2v - mx) : 0.f;
    float sm = e0 + e1 + e2;
#pragma unroll
    for (int o = 8; o > 0; o >>= 1) sm += __shfl_xor(sm, o);
    const float rinv = 1.f / sm;
    satt[tok * 40 + rr]      = e0 * rinv;   // satt aliases cap buf0 (dead after p=3? buf0 last read p=2)
    satt[tok * 40 + rr + 16] = e1 * rinv;
    if (rr < 4) satt[tok * 40 + rr + 32] = e2 * rinv;
  }
  lds_barrier();

  // ---------------- Phase B: out[t][d] = sum_r attn[t][r] * img[r][d] --------------
  // Barrier-free. Thread owns column d = tid; img column from persistent LDS
  // (bf16 -> f32 via <<16), attn via broadcast float4 reads, coalesced stores.
  float ic[RREG];
#pragma unroll
  for (int r = 0; r < RREG; ++r) {
    unsigned int u = simg[r * IMG_STRIDE + tid];
    ic[r] = __uint_as_float(u << 16);
  }
#pragma unroll 2
  for (int t = 0; t < TTOK; ++t) {
    const float4* ap4 = (const float4*)(satt + t * 40);
    float p0 = 0.f, p1 = 0.f, p2 = 0.f, p3 = 0.f;
#pragma unroll
    for (int r4 = 0; r4 < 9; ++r4) {     // 9*4 = 36 rows exactly
      float4 a4 = ap4[r4];
      p0 += a4.x * ic[r4 * 4 + 0];
      p1 += a4.y * ic[r4 * 4 + 1];
      p2 += a4.z * ic[r4 * 4 + 2];
      p3 += a4.w * ic[r4 * 4 + 3];
    }
    outb[(size_t)t * DDIM + tid] = (p0 + p1) + (p2 + p3);
  }
}

extern "C" void kernel_launch(void* const* d_in, const int* in_sizes, int n_in,
                              void* d_out, int out_size, void* d_ws, size_t ws_size,
                              hipStream_t stream) {
  const float* img = (const float*)d_in[0];   // (256, 36, 1024) fp32
  const float* cap = (const float*)d_in[1];   // (256, 64, 1024) fp32
  // d_in[2] = cap_mask, unused by reference forward
  float* out = (float*)d_out;                 // (256, 64, 1024) fp32
  scan_fused<<<dim3(256), dim3(1024), 0, stream>>>(img, cap, out);
}